// Round 4
// baseline (404.088 us; speedup 1.0000x reference)
//
#include <hip/hip_runtime.h>
#include <hip/hip_bf16.h>
#include <math.h>

#define NN 10000
#define NE 131072

typedef __attribute__((ext_vector_type(8))) short short8;
typedef __attribute__((ext_vector_type(4))) float f32x4;

__device__ __forceinline__ float silu_f(float x) {
    return x / (1.0f + __expf(-x));
}

// round-to-nearest-even f32 -> bf16 (finite inputs only)
__device__ __forceinline__ unsigned short f2bf(float f) {
    unsigned int u = __float_as_uint(f);
    u += 0x7FFFu + ((u >> 16) & 1u);
    return (unsigned short)(u >> 16);
}

// packed pair via HW v_cvt_pk_bf16_f32 (x = low half)
__device__ __forceinline__ unsigned int pk_bf16(float lo, float hi) {
    __hip_bfloat162 h = __float22bfloat162_rn(float2{lo, hi});
    return *reinterpret_cast<unsigned int*>(&h);
}

// ---------------------------------------------------------------------------
// Kernel 1: per-node MLP  embed(16) -> 64 -> 32 -> 8  (Ai)
// ---------------------------------------------------------------------------
__global__ __launch_bounds__(256)
void node_mlp_kernel(const int* __restrict__ A,
                     const float* __restrict__ emb_tab,
                     const float* __restrict__ W1, const float* __restrict__ b1,
                     const float* __restrict__ W2, const float* __restrict__ b2,
                     const float* __restrict__ W3, const float* __restrict__ b3,
                     float* __restrict__ Ai)
{
    int n = blockIdx.x * blockDim.x + threadIdx.x;
    if (n >= NN) return;
    int a = A[n];
    float h[16];
#pragma unroll
    for (int i = 0; i < 16; ++i) h[i] = emb_tab[a * 16 + i];

    float h1[64];
#pragma unroll
    for (int j = 0; j < 64; ++j) h1[j] = b1[j];
#pragma unroll
    for (int i = 0; i < 16; ++i) {
        float hv = h[i];
#pragma unroll
        for (int j = 0; j < 64; ++j) h1[j] += hv * W1[i * 64 + j];
    }
#pragma unroll
    for (int j = 0; j < 64; ++j) h1[j] = silu_f(h1[j]);

    float h2[32];
#pragma unroll
    for (int j = 0; j < 32; ++j) h2[j] = b2[j];
#pragma unroll
    for (int i = 0; i < 64; ++i) {
        float hv = h1[i];
#pragma unroll
        for (int j = 0; j < 32; ++j) h2[j] += hv * W2[i * 32 + j];
    }
#pragma unroll
    for (int j = 0; j < 32; ++j) h2[j] = silu_f(h2[j]);

#pragma unroll
    for (int j = 0; j < 8; ++j) {
        float s = b3[j];
#pragma unroll
        for (int i = 0; i < 32; ++i) s += h2[i] * W3[i * 8 + j];
        Ai[n * 8 + j] = s;
    }
}

// ---------------------------------------------------------------------------
// Kernel 2: per-edge geometry + radial MLP -> w3 (bf16, transposed [64][NE])
//           + unit vectors [NE*3]
// Block = 64, __launch_bounds__(64): VGPR cap 512 keeps the ~150-float live
// set in registers (round-2's 128-VGPR build spilled and ran 700 us).
// ---------------------------------------------------------------------------
__global__ __launch_bounds__(64)
void edge_mlp_kernel(const float* __restrict__ pos,
                     const int* __restrict__ batch,
                     const int* __restrict__ esrc,
                     const int* __restrict__ edst,
                     const float* __restrict__ shifts,
                     const float* __restrict__ cell,
                     const float* __restrict__ fcW1,
                     const float* __restrict__ fcW2,
                     const float* __restrict__ fcW3,
                     unsigned short* __restrict__ w3gT,
                     float* __restrict__ unit)
{
    int e = blockIdx.x * 64 + threadIdx.x;
    int s = esrc[e], d = edst[e];
    int b = batch[s];
    const float* C = cell + b * 9;
    float sx = shifts[e * 3 + 0], sy = shifts[e * 3 + 1], sz = shifts[e * 3 + 2];
    float vx = pos[d * 3 + 0] - pos[s * 3 + 0] + sx * C[0] + sy * C[3] + sz * C[6];
    float vy = pos[d * 3 + 1] - pos[s * 3 + 1] + sx * C[1] + sy * C[4] + sz * C[7];
    float vz = pos[d * 3 + 2] - pos[s * 3 + 2] + sx * C[2] + sy * C[5] + sz * C[8];
    float len = sqrtf(vx * vx + vy * vy + vz * vz);
    float inv = 1.0f / fmaxf(len, 1e-9f);
    unit[e * 3 + 0] = vx * inv;
    unit[e * 3 + 1] = vy * inv;
    unit[e * 3 + 2] = vz * inv;

    // soft_one_hot: the sqrt(10) of emb and /sqrt(10) of fc_W1 cancel.
    float embv[10];
    float base = len * 2.75f;
#pragma unroll
    for (int i = 0; i < 10; ++i) {
        float dd = base - (float)(i + 1);
        embv[i] = __expf(-dd * dd) * (1.0f / 1.12f);
    }

    // layer 1: w1 = silu(emb @ fcW1)
    float w1v[64];
#pragma unroll
    for (int j = 0; j < 64; ++j) w1v[j] = 0.f;
#pragma unroll
    for (int i = 0; i < 10; ++i) {
        float hv = embv[i];
#pragma unroll
        for (int j = 0; j < 64; ++j) w1v[j] += hv * fcW1[i * 64 + j];
    }
#pragma unroll
    for (int j = 0; j < 64; ++j) w1v[j] = silu_f(w1v[j]);

    // layer 2: w2 = silu(w1 @ fcW2 / 8), chunks of 16 outputs
    float w2v[64];
#pragma unroll
    for (int jc = 0; jc < 4; ++jc) {
        float accv[16];
#pragma unroll
        for (int j = 0; j < 16; ++j) accv[j] = 0.f;
#pragma unroll
        for (int i = 0; i < 64; ++i) {
            float hv = w1v[i];
#pragma unroll
            for (int j = 0; j < 16; ++j)
                accv[j] += hv * fcW2[i * 64 + jc * 16 + j];
        }
#pragma unroll
        for (int j = 0; j < 16; ++j) w2v[jc * 16 + j] = silu_f(accv[j] * 0.125f);
    }

    // layer 3: w3 = silu(w2 @ fcW3 / 8) -> bf16, transposed global store
#pragma unroll
    for (int jc = 0; jc < 4; ++jc) {
        float accv[16];
#pragma unroll
        for (int j = 0; j < 16; ++j) accv[j] = 0.f;
#pragma unroll
        for (int i = 0; i < 64; ++i) {
            float hv = w2v[i];
#pragma unroll
            for (int j = 0; j < 16; ++j)
                accv[j] += hv * fcW3[i * 64 + jc * 16 + j];
        }
#pragma unroll
        for (int j = 0; j < 16; ++j)
            w3gT[(jc * 16 + j) * NE + e] = f2bf(silu_f(accv[j] * 0.125f));
    }
}

// ---------------------------------------------------------------------------
// Kernel 3: build B = fc_W4 as bf16 MFMA fragments, P-scheme order.
// Fragment f = (k*2 + h)*2 + nt   (k in [0,64), h = uv-half, nt = wc-tile)
// Within fragment (512 bf16): element (lane, j) with q=lane>>4, n=lane&15:
//   B[kdim = q*8+j][col = n]  ->  fcW4[k][uv = h*32+q*8+j][wc = nt*16+n]
// ---------------------------------------------------------------------------
__global__ __launch_bounds__(256)
void prep_B_kernel(const float* __restrict__ fcW4, unsigned short* __restrict__ Bg)
{
    int i = blockIdx.x * 256 + threadIdx.x;   // [0, 131072)
    int j    = i & 7;
    int lane = (i >> 3) & 63;
    int nt   = (i >> 9) & 1;
    int h    = (i >> 10) & 1;
    int k    = i >> 11;
    int q = lane >> 4, n = lane & 15;
    int uv = h * 32 + q * 8 + j;
    int wc = nt * 16 + n;
    float v;
    if (wc < 16)      v = fcW4[k * 1792 + uv * 16 + wc];
    else if (wc < 24) v = fcW4[k * 1792 + 1024 + uv * 8 + (wc - 16)];
    else if (wc < 28) v = fcW4[k * 1792 + 1536 + uv * 4 + (wc - 24)];
    else              v = 0.0f;
    Bg[i] = f2bf(v);
}

// ---------------------------------------------------------------------------
// Kernel 4: P-operand MFMA contraction.
//   out[e,wc] = sum_k w3[e,k] * Q_k[e,wc],  Q_k = P[e,:] @ W4[k,:,:]
//   P[e,uv] = As[u]*Ad[v]  — MFMA A-operand, k-INVARIANT (built once).
// Block 256 thr = 4 waves x 64 edges. w3 in LDS [k][256] bf16 (broadcast
// b64 reads). B read L2-direct (256 KB, L2-resident) with next-k prefetch.
// ---------------------------------------------------------------------------
__global__ __launch_bounds__(256, 3)
void gemm_kernel(const int* __restrict__ esrc,
                 const int* __restrict__ edst,
                 const float* __restrict__ Ai,
                 const unsigned short* __restrict__ w3gT,
                 const float* __restrict__ unit,
                 const unsigned short* __restrict__ Bg,
                 float* __restrict__ outAcc,
                 float* __restrict__ counts)
{
    __shared__ unsigned short w3s[64 * 256];   // [k][block-edge] bf16, 32 KB

    const int tid  = threadIdx.x;
    const int wave = tid >> 6;
    const int lane = tid & 63;
    const int q    = lane >> 4;
    const int n    = lane & 15;
    const int be0  = blockIdx.x * 256;
    const int ew0  = be0 + wave * 64;          // wave's first edge

    // ---- stage w3 [k][256] via global_load_lds (lane-contiguous dst) ----
    {
        const uint4* gsrc = (const uint4*)w3gT;  // [64][NE/8] uint4
#pragma unroll
        for (int it = 0; it < 8; ++it) {
            int idx = it * 256 + tid;            // uint4 index, 0..2047
            int k   = idx >> 5;                  // 32 uint4 per k-row
            int seg = idx & 31;
            const uint4* gp = gsrc + (size_t)k * (NE / 8) + (be0 / 8) + seg;
            uint4* lbase = ((uint4*)w3s) + it * 256 + wave * 64;  // wave-uniform
            __builtin_amdgcn_global_load_lds(
                (const __attribute__((address_space(1))) unsigned int*)gp,
                (__attribute__((address_space(3))) unsigned int*)lbase,
                16, 0, 0);
        }
    }

    // ---- build k-invariant P fragments: P[e, uv=h*32+q*8+j] = As[h*4+q]*Ad[j]
    union AF { unsigned int u[4]; short8 s8; };
    AF P[4][2];
#pragma unroll
    for (int t = 0; t < 4; ++t) {
        int e = ew0 + t * 16 + n;
        int s = esrc[e], d = edst[e];
        float As0 = Ai[s * 8 + q];
        float As1 = Ai[s * 8 + 4 + q];
        float4 d0 = *(const float4*)&Ai[d * 8];
        float4 d1 = *(const float4*)&Ai[d * 8 + 4];
        float Ad[8] = {d0.x, d0.y, d0.z, d0.w, d1.x, d1.y, d1.z, d1.w};
#pragma unroll
        for (int h = 0; h < 2; ++h) {
            float s0 = h ? As1 : As0;
            P[t][h].u[0] = pk_bf16(s0 * Ad[0], s0 * Ad[1]);
            P[t][h].u[1] = pk_bf16(s0 * Ad[2], s0 * Ad[3]);
            P[t][h].u[2] = pk_bf16(s0 * Ad[4], s0 * Ad[5]);
            P[t][h].u[3] = pk_bf16(s0 * Ad[6], s0 * Ad[7]);
        }
    }

    __syncthreads();   // w3 staged

    f32x4 out[4][2];
#pragma unroll
    for (int t = 0; t < 4; ++t)
#pragma unroll
        for (int nt = 0; nt < 2; ++nt)
            out[t][nt] = (f32x4){0.f, 0.f, 0.f, 0.f};

    const f32x4 Z4 = (f32x4){0.f, 0.f, 0.f, 0.f};
    const short8* Bp = (const short8*)Bg;      // fragment f at Bp[f*64 + lane]

    short8 Bc[2][2];
#pragma unroll
    for (int h = 0; h < 2; ++h)
#pragma unroll
        for (int nt = 0; nt < 2; ++nt)
            Bc[h][nt] = Bp[(h * 2 + nt) * 64 + lane];

#pragma unroll 2
    for (int k = 0; k < 64; ++k) {
        // prefetch next k's B fragments (L2-hot)
        short8 Bn[2][2];
        if (k < 63) {
#pragma unroll
            for (int h = 0; h < 2; ++h)
#pragma unroll
                for (int nt = 0; nt < 2; ++nt)
                    Bn[h][nt] = Bp[(((k + 1) * 2 + h) * 2 + nt) * 64 + lane];
        }

        // w3 weights for this lane's 16 C-rows: 4 broadcast b64 reads
        float w3f[4][4];
#pragma unroll
        for (int t = 0; t < 4; ++t) {
            uint2 v = *(const uint2*)&w3s[k * 256 + wave * 64 + t * 16 + q * 4];
            w3f[t][0] = __uint_as_float(v.x << 16);
            w3f[t][1] = __uint_as_float(v.x & 0xFFFF0000u);
            w3f[t][2] = __uint_as_float(v.y << 16);
            w3f[t][3] = __uint_as_float(v.y & 0xFFFF0000u);
        }

#pragma unroll
        for (int t = 0; t < 4; ++t) {
#pragma unroll
            for (int nt = 0; nt < 2; ++nt) {
                f32x4 Q = __builtin_amdgcn_mfma_f32_16x16x32_bf16(
                    P[t][0].s8, Bc[0][nt], Z4, 0, 0, 0);
                Q = __builtin_amdgcn_mfma_f32_16x16x32_bf16(
                    P[t][1].s8, Bc[1][nt], Q, 0, 0, 0);
#pragma unroll
                for (int r = 0; r < 4; ++r)
                    out[t][nt][r] += w3f[t][r] * Q[r];
            }
        }

        if (k < 63) {
#pragma unroll
            for (int h = 0; h < 2; ++h)
#pragma unroll
                for (int nt = 0; nt < 2; ++nt)
                    Bc[h][nt] = Bn[h][nt];
        }
    }

    // ---- epilogue: C/D layout col = n (wc), row = q*4 + r (edge) ----
    const float sc   = 1.0f / 64.0f;
    const float s3c  = 1.7320508075688772f;
    const float s5c  = 2.2360679774997896f;
    const float s15c = 3.872983346207417f;
#pragma unroll
    for (int t = 0; t < 4; ++t) {
#pragma unroll
        for (int r = 0; r < 4; ++r) {
            int e = ew0 + t * 16 + q * 4 + r;
            int d = edst[e];
            float* orow = outAcc + d * 60;
            atomicAdd(orow + n, out[t][0][r] * sc);   // l0, wc = n
            float a1 = out[t][1][r] * sc;             // wc = 16+n
            if (n < 12) {
                float ux = unit[e * 3], uy = unit[e * 3 + 1], uz = unit[e * 3 + 2];
                if (n < 8) {
                    atomicAdd(orow + 16 + n * 3 + 0, a1 * (s3c * ux));
                    atomicAdd(orow + 16 + n * 3 + 1, a1 * (s3c * uy));
                    atomicAdd(orow + 16 + n * 3 + 2, a1 * (s3c * uz));
                } else {
                    int w = n - 8;
                    atomicAdd(orow + 40 + w * 5 + 0, a1 * (s15c * ux * uz));
                    atomicAdd(orow + 40 + w * 5 + 1, a1 * (s15c * ux * uy));
                    atomicAdd(orow + 40 + w * 5 + 2, a1 * (s5c * (uy * uy - 0.5f * (ux * ux + uz * uz))));
                    atomicAdd(orow + 40 + w * 5 + 3, a1 * (s15c * uy * uz));
                    atomicAdd(orow + 40 + w * 5 + 4, a1 * (0.5f * s15c * (uz * uz - ux * ux)));
                }
            }
            if (n == 0) atomicAdd(counts + d, 1.0f);
        }
    }
}

// ---------------------------------------------------------------------------
// Kernel 5: divide by max(counts, 1)
// ---------------------------------------------------------------------------
__global__ __launch_bounds__(256)
void finalize_kernel(float* __restrict__ out, const float* __restrict__ counts)
{
    int i = blockIdx.x * 256 + threadIdx.x;
    if (i >= NN * 60) return;
    int nd = i / 60;
    out[i] = out[i] / fmaxf(counts[nd], 1.0f);
}

extern "C" void kernel_launch(void* const* d_in, const int* in_sizes, int n_in,
                              void* d_out, int out_size, void* d_ws, size_t ws_size,
                              hipStream_t stream)
{
    const float* pos     = (const float*)d_in[0];
    const int*   A       = (const int*)d_in[1];
    const int*   batch   = (const int*)d_in[2];
    const int*   esrc    = (const int*)d_in[3];
    const int*   edst    = (const int*)d_in[4];
    const float* shifts  = (const float*)d_in[5];
    const float* cell    = (const float*)d_in[6];
    const float* emb_tab = (const float*)d_in[7];
    const float* fitW1   = (const float*)d_in[8];
    const float* fitb1   = (const float*)d_in[9];
    const float* fitW2   = (const float*)d_in[10];
    const float* fitb2   = (const float*)d_in[11];
    const float* fitW3   = (const float*)d_in[12];
    const float* fitb3   = (const float*)d_in[13];
    const float* fcW1    = (const float*)d_in[14];
    const float* fcW2    = (const float*)d_in[15];
    const float* fcW3    = (const float*)d_in[16];
    const float* fcW4    = (const float*)d_in[17];

    float* out = (float*)d_out;

    // workspace layout (floats)
    float* ws      = (float*)d_ws;
    float* Ai      = ws;                              // 80000
    float* counts  = ws + 80000;                      // 10000
    float* unit    = ws + 90000;                      // NE*3 = 393216
    unsigned short* w3gT = (unsigned short*)(ws + 483216);           // NE*64 bf16
    unsigned short* BgU  = (unsigned short*)(ws + 483216 + 4194304); // 131072 bf16
    hipMemsetAsync(d_out, 0, (size_t)NN * 60 * sizeof(float), stream);
    hipMemsetAsync(counts, 0, (size_t)NN * sizeof(float), stream);

    node_mlp_kernel<<<(NN + 255) / 256, 256, 0, stream>>>(
        A, emb_tab, fitW1, fitb1, fitW2, fitb2, fitW3, fitb3, Ai);

    edge_mlp_kernel<<<NE / 64, 64, 0, stream>>>(
        pos, batch, esrc, edst, shifts, cell, fcW1, fcW2, fcW3, w3gT, unit);

    prep_B_kernel<<<131072 / 256, 256, 0, stream>>>(fcW4, BgU);

    gemm_kernel<<<NE / 256, 256, 0, stream>>>(
        esrc, edst, Ai, w3gT, unit, BgU, out, counts);

    finalize_kernel<<<(NN * 60 + 255) / 256, 256, 0, stream>>>(out, counts);
}

// Round 5
// 318.913 us; speedup vs baseline: 1.2671x; 1.2671x over previous
//
#include <hip/hip_runtime.h>
#include <hip/hip_bf16.h>
#include <math.h>

#define NN 10000
#define NE 131072

typedef __attribute__((ext_vector_type(8))) short short8;
typedef __attribute__((ext_vector_type(4))) float f32x4;

__device__ __forceinline__ float silu_f(float x) {
    return x / (1.0f + __expf(-x));
}

// round-to-nearest-even f32 -> bf16 (finite inputs only)
__device__ __forceinline__ unsigned short f2bf(float f) {
    unsigned int u = __float_as_uint(f);
    u += 0x7FFFu + ((u >> 16) & 1u);
    return (unsigned short)(u >> 16);
}

// packed pair via HW v_cvt_pk_bf16_f32 (x = low half)
__device__ __forceinline__ unsigned int pk_bf16(float lo, float hi) {
    __hip_bfloat162 h = __float22bfloat162_rn(float2{lo, hi});
    return *reinterpret_cast<unsigned int*>(&h);
}

// ---------------------------------------------------------------------------
// Sort machinery: counting sort of edges by dst (10000 bins).
// ---------------------------------------------------------------------------
__global__ __launch_bounds__(256)
void hist_kernel(const int* __restrict__ edst, int* __restrict__ hist)
{
    int e = blockIdx.x * 256 + threadIdx.x;
    if (e < NE) atomicAdd(&hist[edst[e]], 1);
}

__global__ __launch_bounds__(256)
void scan_kernel(const int* __restrict__ hist, int* __restrict__ offsets)
{
    __shared__ int part[256];
    int tid = threadIdx.x;
    int base = tid * 40, s = 0;
    for (int r = 0; r < 40; ++r) {
        int idx = base + r;
        if (idx < NN) s += hist[idx];
    }
    part[tid] = s;
    __syncthreads();
    if (tid == 0) {
        int run = 0;
        for (int i = 0; i < 256; ++i) { int t = part[i]; part[i] = run; run += t; }
        offsets[NN] = run;   // == NE
    }
    __syncthreads();
    int run = part[tid];
    for (int r = 0; r < 40; ++r) {
        int idx = base + r;
        if (idx < NN) { offsets[idx] = run; run += hist[idx]; }
    }
}

__global__ __launch_bounds__(256)
void rank_kernel(const int* __restrict__ edst, const int* __restrict__ offsets,
                 int* __restrict__ poscnt, int* __restrict__ sortidx)
{
    int e = blockIdx.x * 256 + threadIdx.x;
    if (e >= NE) return;
    int d = edst[e];
    int p = offsets[d] + atomicAdd(&poscnt[d], 1);
    sortidx[p] = e;
}

// ---------------------------------------------------------------------------
// Kernel: per-node MLP  embed(16) -> 64 -> 32 -> 8  (Ai)
// ---------------------------------------------------------------------------
__global__ __launch_bounds__(256)
void node_mlp_kernel(const int* __restrict__ A,
                     const float* __restrict__ emb_tab,
                     const float* __restrict__ W1, const float* __restrict__ b1,
                     const float* __restrict__ W2, const float* __restrict__ b2,
                     const float* __restrict__ W3, const float* __restrict__ b3,
                     float* __restrict__ Ai)
{
    int n = blockIdx.x * blockDim.x + threadIdx.x;
    if (n >= NN) return;
    int a = A[n];
    float h[16];
#pragma unroll
    for (int i = 0; i < 16; ++i) h[i] = emb_tab[a * 16 + i];

    float h1[64];
#pragma unroll
    for (int j = 0; j < 64; ++j) h1[j] = b1[j];
#pragma unroll
    for (int i = 0; i < 16; ++i) {
        float hv = h[i];
#pragma unroll
        for (int j = 0; j < 64; ++j) h1[j] += hv * W1[i * 64 + j];
    }
#pragma unroll
    for (int j = 0; j < 64; ++j) h1[j] = silu_f(h1[j]);

    float h2[32];
#pragma unroll
    for (int j = 0; j < 32; ++j) h2[j] = b2[j];
#pragma unroll
    for (int i = 0; i < 64; ++i) {
        float hv = h1[i];
#pragma unroll
        for (int j = 0; j < 32; ++j) h2[j] += hv * W2[i * 32 + j];
    }
#pragma unroll
    for (int j = 0; j < 32; ++j) h2[j] = silu_f(h2[j]);

#pragma unroll
    for (int j = 0; j < 8; ++j) {
        float s = b3[j];
#pragma unroll
        for (int i = 0; i < 32; ++i) s += h2[i] * W3[i * 8 + j];
        Ai[n * 8 + j] = s;
    }
}

// ---------------------------------------------------------------------------
// Kernel: per-edge geometry + radial MLP, processed in SORTED order.
// Thread i handles sorted edge i = sortidx-permuted edge. Writes w3 bf16
// transposed [64][NE] at column i, unit[i], and sorted esrc/edst copies.
// Block=64 / __launch_bounds__(64): VGPR cap 512 keeps the ~150-float live
// set unspilled (round-2 lesson: 128-VGPR build spilled, 700 us).
// ---------------------------------------------------------------------------
__global__ __launch_bounds__(64)
void edge_mlp_kernel(const float* __restrict__ pos,
                     const int* __restrict__ batch,
                     const int* __restrict__ esrc,
                     const int* __restrict__ edst,
                     const float* __restrict__ shifts,
                     const float* __restrict__ cell,
                     const float* __restrict__ fcW1,
                     const float* __restrict__ fcW2,
                     const float* __restrict__ fcW3,
                     const int* __restrict__ sortidx,
                     int* __restrict__ esrc_s,
                     int* __restrict__ edst_s,
                     unsigned short* __restrict__ w3gT,
                     float* __restrict__ unit)
{
    int i = blockIdx.x * 64 + threadIdx.x;
    int e = sortidx[i];
    int s = esrc[e], d = edst[e];
    esrc_s[i] = s;
    edst_s[i] = d;
    int b = batch[s];
    const float* C = cell + b * 9;
    float sx = shifts[e * 3 + 0], sy = shifts[e * 3 + 1], sz = shifts[e * 3 + 2];
    float vx = pos[d * 3 + 0] - pos[s * 3 + 0] + sx * C[0] + sy * C[3] + sz * C[6];
    float vy = pos[d * 3 + 1] - pos[s * 3 + 1] + sx * C[1] + sy * C[4] + sz * C[7];
    float vz = pos[d * 3 + 2] - pos[s * 3 + 2] + sx * C[2] + sy * C[5] + sz * C[8];
    float len = sqrtf(vx * vx + vy * vy + vz * vz);
    float inv = 1.0f / fmaxf(len, 1e-9f);
    unit[i * 3 + 0] = vx * inv;
    unit[i * 3 + 1] = vy * inv;
    unit[i * 3 + 2] = vz * inv;

    // soft_one_hot: the sqrt(10) of emb and /sqrt(10) of fc_W1 cancel.
    float embv[10];
    float base = len * 2.75f;
#pragma unroll
    for (int ii = 0; ii < 10; ++ii) {
        float dd = base - (float)(ii + 1);
        embv[ii] = __expf(-dd * dd) * (1.0f / 1.12f);
    }

    // layer 1: w1 = silu(emb @ fcW1)
    float w1v[64];
#pragma unroll
    for (int j = 0; j < 64; ++j) w1v[j] = 0.f;
#pragma unroll
    for (int ii = 0; ii < 10; ++ii) {
        float hv = embv[ii];
#pragma unroll
        for (int j = 0; j < 64; ++j) w1v[j] += hv * fcW1[ii * 64 + j];
    }
#pragma unroll
    for (int j = 0; j < 64; ++j) w1v[j] = silu_f(w1v[j]);

    // layer 2: w2 = silu(w1 @ fcW2 / 8), chunks of 16 outputs
    float w2v[64];
#pragma unroll
    for (int jc = 0; jc < 4; ++jc) {
        float accv[16];
#pragma unroll
        for (int j = 0; j < 16; ++j) accv[j] = 0.f;
#pragma unroll
        for (int ii = 0; ii < 64; ++ii) {
            float hv = w1v[ii];
#pragma unroll
            for (int j = 0; j < 16; ++j)
                accv[j] += hv * fcW2[ii * 64 + jc * 16 + j];
        }
#pragma unroll
        for (int j = 0; j < 16; ++j) w2v[jc * 16 + j] = silu_f(accv[j] * 0.125f);
    }

    // layer 3: w3 = silu(w2 @ fcW3 / 8) -> bf16, transposed global store
#pragma unroll
    for (int jc = 0; jc < 4; ++jc) {
        float accv[16];
#pragma unroll
        for (int j = 0; j < 16; ++j) accv[j] = 0.f;
#pragma unroll
        for (int ii = 0; ii < 64; ++ii) {
            float hv = w2v[ii];
#pragma unroll
            for (int j = 0; j < 16; ++j)
                accv[j] += hv * fcW3[ii * 64 + jc * 16 + j];
        }
#pragma unroll
        for (int j = 0; j < 16; ++j)
            w3gT[(jc * 16 + j) * NE + i] = f2bf(silu_f(accv[j] * 0.125f));
    }
}

// ---------------------------------------------------------------------------
// Kernel: build B = fc_W4 as bf16 MFMA fragments (P-scheme order).
// Fragment f = (k*2 + h)*2 + nt; within fragment, lane (q,n), j:
//   B[kdim=q*8+j][col=n] = fcW4[k][uv=h*32+q*8+j][wc=nt*16+n], wc>=28 -> 0
// ---------------------------------------------------------------------------
__global__ __launch_bounds__(256)
void prep_B_kernel(const float* __restrict__ fcW4, unsigned short* __restrict__ Bg)
{
    int i = blockIdx.x * 256 + threadIdx.x;   // [0, 131072)
    int j    = i & 7;
    int lane = (i >> 3) & 63;
    int nt   = (i >> 9) & 1;
    int h    = (i >> 10) & 1;
    int k    = i >> 11;
    int q = lane >> 4, n = lane & 15;
    int uv = h * 32 + q * 8 + j;
    int wc = nt * 16 + n;
    float v;
    if (wc < 16)      v = fcW4[k * 1792 + uv * 16 + wc];
    else if (wc < 24) v = fcW4[k * 1792 + 1024 + uv * 8 + (wc - 16)];
    else if (wc < 28) v = fcW4[k * 1792 + 1536 + uv * 4 + (wc - 24)];
    else              v = 0.0f;
    Bg[i] = f2bf(v);
}

// ---------------------------------------------------------------------------
// Kernel: P-operand MFMA contraction, sorted-edge order, atomic-free.
//   feat[e, wc] = sum_k w3[e,k] * (P[e,:] @ W4[k,:,:])[wc]
// 128 edges/block (4 waves x 32 edges). B double-buffered through LDS in
// 4-k chunks (16 KB) via global_load_lds; w3 staged in LDS [64][128].
// Epilogue: coalesced raw feature-row stores (no atomics).
// ---------------------------------------------------------------------------
__global__ __launch_bounds__(256, 3)
void gemm_kernel(const int* __restrict__ esrc_s,
                 const int* __restrict__ edst_s,
                 const float* __restrict__ Ai,
                 const unsigned short* __restrict__ w3gT,
                 const unsigned short* __restrict__ Bg,
                 float* __restrict__ featbuf)
{
    __shared__ __align__(16) unsigned short w3s[64 * 128];   // 16 KB
    __shared__ __align__(16) unsigned char Bs[2][16384];     // 32 KB

    const int tid  = threadIdx.x;
    const int wave = tid >> 6;
    const int lane = tid & 63;
    const int q    = lane >> 4;
    const int n    = lane & 15;
    const int be0  = blockIdx.x * 128;
    const int ew0  = be0 + wave * 32;

    // stage w3 [64][128] bf16 (256 B per k-row)
#pragma unroll
    for (int it = 0; it < 4; ++it) {
        int idx = it * 256 + tid;            // 16B unit, 0..1023
        int k = idx >> 4, seg = idx & 15;
        const unsigned short* gp = w3gT + (size_t)k * NE + be0 + seg * 8;
        unsigned char* lb = ((unsigned char*)w3s) + (it * 256 + wave * 64) * 16;
        __builtin_amdgcn_global_load_lds(
            (const __attribute__((address_space(1))) unsigned int*)gp,
            (__attribute__((address_space(3))) unsigned int*)lb, 16, 0, 0);
    }

    // B chunk stager: chunk c = k in [4c, 4c+4), 16 KB contiguous in Bg
    auto stageB = [&](int c, int buf) {
#pragma unroll
        for (int it = 0; it < 4; ++it) {
            int idx = it * 256 + tid;
            const unsigned char* gp = ((const unsigned char*)Bg) + c * 16384 + idx * 16;
            unsigned char* lb = Bs[buf] + (it * 256 + wave * 64) * 16;
            __builtin_amdgcn_global_load_lds(
                (const __attribute__((address_space(1))) unsigned int*)gp,
                (__attribute__((address_space(3))) unsigned int*)lb, 16, 0, 0);
        }
    };
    stageB(0, 0);

    // k-invariant P fragments: P[e, uv=h*32+q*8+j] = As[h*4+q]*Ad[j]
    union AF { unsigned int u[4]; short8 s8; };
    AF P[2][2];
#pragma unroll
    for (int t = 0; t < 2; ++t) {
        int e = ew0 + t * 16 + n;
        int s = esrc_s[e], d = edst_s[e];
        float As0 = Ai[s * 8 + q];
        float As1 = Ai[s * 8 + 4 + q];
        float4 d0 = *(const float4*)&Ai[d * 8];
        float4 d1 = *(const float4*)&Ai[d * 8 + 4];
        float Ad[8] = {d0.x, d0.y, d0.z, d0.w, d1.x, d1.y, d1.z, d1.w};
#pragma unroll
        for (int h = 0; h < 2; ++h) {
            float s0 = h ? As1 : As0;
            P[t][h].u[0] = pk_bf16(s0 * Ad[0], s0 * Ad[1]);
            P[t][h].u[1] = pk_bf16(s0 * Ad[2], s0 * Ad[3]);
            P[t][h].u[2] = pk_bf16(s0 * Ad[4], s0 * Ad[5]);
            P[t][h].u[3] = pk_bf16(s0 * Ad[6], s0 * Ad[7]);
        }
    }

    __syncthreads();   // w3 + B chunk 0 staged

    f32x4 out[2][2];
#pragma unroll
    for (int t = 0; t < 2; ++t)
#pragma unroll
        for (int nt = 0; nt < 2; ++nt)
            out[t][nt] = (f32x4){0.f, 0.f, 0.f, 0.f};
    const f32x4 Z4 = (f32x4){0.f, 0.f, 0.f, 0.f};

#pragma unroll 1
    for (int c = 0; c < 16; ++c) {
        int cur = c & 1;
        if (c < 15) stageB(c + 1, cur ^ 1);
#pragma unroll
        for (int kk = 0; kk < 4; ++kk) {
            int k = c * 4 + kk;
            float w3f[2][4];
#pragma unroll
            for (int t = 0; t < 2; ++t) {
                uint2 v = *(const uint2*)&w3s[k * 128 + wave * 32 + t * 16 + q * 4];
                w3f[t][0] = __uint_as_float(v.x << 16);
                w3f[t][1] = __uint_as_float(v.x & 0xFFFF0000u);
                w3f[t][2] = __uint_as_float(v.y << 16);
                w3f[t][3] = __uint_as_float(v.y & 0xFFFF0000u);
            }
            short8 Bf[2][2];
#pragma unroll
            for (int h = 0; h < 2; ++h)
#pragma unroll
                for (int nt = 0; nt < 2; ++nt)
                    Bf[h][nt] = *(const short8*)(Bs[cur] + ((kk * 2 + h) * 2 + nt) * 1024 + lane * 16);
#pragma unroll
            for (int t = 0; t < 2; ++t) {
#pragma unroll
                for (int nt = 0; nt < 2; ++nt) {
                    f32x4 Q = __builtin_amdgcn_mfma_f32_16x16x32_bf16(
                        P[t][0].s8, Bf[0][nt], Z4, 0, 0, 0);
                    Q = __builtin_amdgcn_mfma_f32_16x16x32_bf16(
                        P[t][1].s8, Bf[1][nt], Q, 0, 0, 0);
#pragma unroll
                    for (int r = 0; r < 4; ++r)
                        out[t][nt][r] += w3f[t][r] * Q[r];
                }
            }
        }
        __syncthreads();
    }

    // epilogue: raw 32-wide feature rows, coalesced (C-layout: col=n, row=q*4+r)
#pragma unroll
    for (int t = 0; t < 2; ++t) {
#pragma unroll
        for (int r = 0; r < 4; ++r) {
            int e = ew0 + t * 16 + q * 4 + r;
            featbuf[e * 32 + n]      = out[t][0][r];
            featbuf[e * 32 + 16 + n] = out[t][1][r];
        }
    }
}

// ---------------------------------------------------------------------------
// Kernel: per-node segment mean over contiguous sorted edges + sh expansion.
// 1 wave per node; lane j owns output column j (j<60).
// ---------------------------------------------------------------------------
__global__ __launch_bounds__(64)
void segment_kernel(const int* __restrict__ offsets,
                    const float* __restrict__ featbuf,
                    const float* __restrict__ unit,
                    float* __restrict__ out)
{
    const float s3c  = 1.7320508075688772f;
    const float s5c  = 2.2360679774997896f;
    const float s15c = 3.872983346207417f;

    int nd = blockIdx.x;
    int j  = threadIdx.x;
    int off0 = offsets[nd], off1 = offsets[nd + 1];

    int c = 0, mode = 0, m = 0;
    if (j < 16)      { c = j; mode = 0; }
    else if (j < 40) { int w = (j - 16) / 3; m = (j - 16) % 3; c = 16 + w; mode = 1; }
    else if (j < 60) { int w = (j - 40) / 5; m = (j - 40) % 5; c = 24 + w; mode = 2; }
    else             { c = 0; mode = 3; }

    float sum = 0.f;
    for (int e = off0; e < off1; ++e) {
        float f = featbuf[e * 32 + c];
        float sh = 1.f;
        if (mode == 1 || mode == 2) {
            float ux = unit[e * 3 + 0], uy = unit[e * 3 + 1], uz = unit[e * 3 + 2];
            if (mode == 1) {
                sh = s3c * (m == 0 ? ux : (m == 1 ? uy : uz));
            } else {
                if (m == 0)      sh = s15c * ux * uz;
                else if (m == 1) sh = s15c * ux * uy;
                else if (m == 2) sh = s5c * (uy * uy - 0.5f * (ux * ux + uz * uz));
                else if (m == 3) sh = s15c * uy * uz;
                else             sh = 0.5f * s15c * (uz * uz - ux * ux);
            }
        }
        sum += f * sh;
    }
    if (j < 60) {
        float cnt = (float)(off1 - off0);
        out[nd * 60 + j] = sum * (1.0f / 64.0f) / fmaxf(cnt, 1.0f);
    }
}

extern "C" void kernel_launch(void* const* d_in, const int* in_sizes, int n_in,
                              void* d_out, int out_size, void* d_ws, size_t ws_size,
                              hipStream_t stream)
{
    const float* pos     = (const float*)d_in[0];
    const int*   A       = (const int*)d_in[1];
    const int*   batch   = (const int*)d_in[2];
    const int*   esrc    = (const int*)d_in[3];
    const int*   edst    = (const int*)d_in[4];
    const float* shifts  = (const float*)d_in[5];
    const float* cell    = (const float*)d_in[6];
    const float* emb_tab = (const float*)d_in[7];
    const float* fitW1   = (const float*)d_in[8];
    const float* fitb1   = (const float*)d_in[9];
    const float* fitW2   = (const float*)d_in[10];
    const float* fitb2   = (const float*)d_in[11];
    const float* fitW3   = (const float*)d_in[12];
    const float* fitb3   = (const float*)d_in[13];
    const float* fcW1    = (const float*)d_in[14];
    const float* fcW2    = (const float*)d_in[15];
    const float* fcW3    = (const float*)d_in[16];
    const float* fcW4    = (const float*)d_in[17];

    float* out = (float*)d_out;

    // workspace layout (all 16B-aligned)
    char* W = (char*)d_ws;
    float* Ai      = (float*)W;  W += (size_t)NN * 8 * 4;     // 320000
    int* sortidx   = (int*)W;    W += (size_t)NE * 4;
    int* esrc_s    = (int*)W;    W += (size_t)NE * 4;
    int* edst_s    = (int*)W;    W += (size_t)NE * 4;
    int* hist      = (int*)W;    W += (size_t)NN * 4;
    int* poscnt    = (int*)W;    W += (size_t)NN * 4;
    int* offsets   = (int*)W;    W += (size_t)(NN + 8) * 4;
    float* unit    = (float*)W;  W += (size_t)NE * 3 * 4;
    unsigned short* w3gT = (unsigned short*)W; W += (size_t)NE * 64 * 2;
    unsigned short* Bg   = (unsigned short*)W; W += (size_t)131072 * 2;
    float* featbuf = (float*)W;  W += (size_t)NE * 32 * 4;

    hipMemsetAsync(hist,   0, (size_t)NN * 4, stream);
    hipMemsetAsync(poscnt, 0, (size_t)NN * 4, stream);

    hist_kernel<<<(NE + 255) / 256, 256, 0, stream>>>(edst, hist);
    scan_kernel<<<1, 256, 0, stream>>>(hist, offsets);
    rank_kernel<<<(NE + 255) / 256, 256, 0, stream>>>(edst, offsets, poscnt, sortidx);

    node_mlp_kernel<<<(NN + 255) / 256, 256, 0, stream>>>(
        A, emb_tab, fitW1, fitb1, fitW2, fitb2, fitW3, fitb3, Ai);

    edge_mlp_kernel<<<NE / 64, 64, 0, stream>>>(
        pos, batch, esrc, edst, shifts, cell, fcW1, fcW2, fcW3,
        sortidx, esrc_s, edst_s, w3gT, unit);

    prep_B_kernel<<<131072 / 256, 256, 0, stream>>>(fcW4, Bg);

    gemm_kernel<<<NE / 128, 256, 0, stream>>>(
        esrc_s, edst_s, Ai, w3gT, Bg, featbuf);

    segment_kernel<<<NN, 64, 0, stream>>>(offsets, featbuf, unit, out);
}